// Round 8
// baseline (205.109 us; speedup 1.0000x reference)
//
#include <hip/hip_runtime.h>
#include <hip/hip_bf16.h>
#include <cstdint>

#define NN 2000   // nodes
#define NNP 2048  // padded nodes
#define NB 32     // batch
#define DD 32     // d_in == d_out
#define HH 64     // hidden
#define EE 16     // env features
#define NP 24     // periods
#define NT 32     // n-tiles of 64 (covers 2048)
#define KSPLIT 4  // k-range split per output tile
#define KITERS (NNP / 64 / KSPLIT)   // 8
#define LSTR 72   // LDS row stride in f16 (144 B: 16B-aligned rows -> b128 ops; 2-way bank alias = free)

typedef _Float16 f16;
typedef _Float16 half8 __attribute__((ext_vector_type(8)));
typedef float f32x4 __attribute__((ext_vector_type(4)));

// ---- fused prologue: [0,512) prep Sb/Tb; [512,768) suppT+resd; [768,2816) zero accbuf ----
__global__ __launch_bounds__(256) void k_pre(const float* __restrict__ envf,
                                             const float* __restrict__ Wenv,
                                             const float* __restrict__ benv,
                                             const float* __restrict__ src,
                                             const float* __restrict__ tgt,
                                             const float* __restrict__ x,
                                             const float* __restrict__ W,
                                             const float* __restrict__ Wres,
                                             const float* __restrict__ bres,
                                             f16* __restrict__ Sb,
                                             f16* __restrict__ Tb,
                                             f16* __restrict__ suppT,
                                             float* __restrict__ resd,
                                             float* __restrict__ accbuf) {
    int blk = blockIdx.x, t = threadIdx.x;
    if (blk < 512) {
        // ---- prep: env = relu(envf@Wenv+b); Sb/Tb[n][p][h] = f16(src/tgt + env) ----
        int n = blk * 4 + (t >> 6), h = t & 63;
        if (n >= NN) {                          // zero pad rows 2000..2047
            for (int p = 0; p < NP; ++p) {
                size_t o = ((size_t)n * NP + p) * HH + h;
                Sb[o] = (f16)0.f; Tb[o] = (f16)0.f;
            }
            return;
        }
        float acc = benv[h];
#pragma unroll
        for (int e = 0; e < EE; ++e) acc = fmaf(envf[n * EE + e], Wenv[e * HH + h], acc);
        acc = fmaxf(acc, 0.f);
        for (int p = 0; p < NP; ++p) {
            size_t i = ((size_t)p * NN + n) * HH + h;
            size_t o = ((size_t)n * NP + p) * HH + h;
            Sb[o] = (f16)(src[i] + acc);
            Tb[o] = (f16)(tgt[i] + acc);
        }
    } else if (blk < 768) {
        // ---- suppT[b][m][k] = f16(x@W) (k zero-padded); resd = relu(x@Wres+bres) ----
        __shared__ float w[DD * DD], wr[DD * DD];
        for (int i = t; i < DD * DD; i += 256) { w[i] = W[i]; wr[i] = Wres[i]; }
        __syncthreads();
        int idx = (blk - 512) * 256 + t;        // b*2048 + node
        int b = idx >> 11, node = idx & (NNP - 1);
        if (node >= NN) {
#pragma unroll
            for (int m = 0; m < DD; ++m) suppT[((size_t)b * DD + m) * NNP + node] = (f16)0.f;
            return;
        }
        float xv[DD];
        const float4* xr = (const float4*)(x + ((size_t)b * NN + node) * DD);
#pragma unroll
        for (int q = 0; q < DD / 4; ++q) {
            float4 v = xr[q];
            xv[4 * q] = v.x; xv[4 * q + 1] = v.y; xv[4 * q + 2] = v.z; xv[4 * q + 3] = v.w;
        }
        float sa[DD], ra[DD];
#pragma unroll
        for (int m = 0; m < DD; ++m) { sa[m] = 0.f; ra[m] = bres[m]; }
#pragma unroll
        for (int d = 0; d < DD; ++d) {
            float xd = xv[d];
#pragma unroll
            for (int m = 0; m < DD; ++m) {
                sa[m] = fmaf(xd, w[d * DD + m], sa[m]);
                ra[m] = fmaf(xd, wr[d * DD + m], ra[m]);
            }
        }
#pragma unroll
        for (int m = 0; m < DD; ++m)
            suppT[((size_t)b * DD + m) * NNP + node] = (f16)sa[m];
        float4* ro = (float4*)(resd + ((size_t)b * NN + node) * DD);
#pragma unroll
        for (int q = 0; q < DD / 4; ++q)
            ro[q] = make_float4(fmaxf(ra[4 * q], 0.f), fmaxf(ra[4 * q + 1], 0.f),
                                fmaxf(ra[4 * q + 2], 0.f), fmaxf(ra[4 * q + 3], 0.f));
    } else {
        // ---- zero accbuf (replaces hipMemsetAsync dispatch) ----
        int i = (blk - 768) * 256 + t;          // float4 units; 2048 blocks cover 524288
        ((float4*)accbuf)[i] = make_float4(0.f, 0.f, 0.f, 0.f);
    }
}

// ---- main: one block per (nt, ks, b); split-K, reg-prefetch staging, atomic accumulate ----
__global__ __launch_bounds__(256) void k_conv2(const f16* __restrict__ Sb,    // [NNP,NP,HH]
                                               const f16* __restrict__ Tb,    // [NNP,NP,HH]
                                               const f16* __restrict__ suppT, // [NB,DD,NNP]
                                               const float* __restrict__ adj, // [NN,NN]
                                               const int* __restrict__ cyc,   // [NB]
                                               float* __restrict__ accbuf) {  // [NB,NNP,DD] f32
    int bi = blockIdx.x;
    int b = bi & 31;                 // b fastest: co-resident blocks share adj n-panel in L2
    int ks = (bi >> 5) & (KSPLIT - 1);
    int nt = bi >> 7;
    int p = cyc[b] % NP; if (p < 0) p += NP;

    __shared__ f16 Tt[64][LSTR];
    __shared__ f16 Pt[64][LSTR];
    __shared__ f16 Sup[DD][LSTR];

    int t = threadIdx.x;
    int w = t >> 6, l = t & 63;
    int u = l & 15, g = l >> 4;      // MFMA lane decomposition
    int wm = w * 16;                 // wave's 16-row slice
    int n0 = nt * 64;

    // GEMM1 A-fragments (S rows), invariant over k-loop. k-map: h = 32s + 8g + j
    const f16* sbase = Sb + ((size_t)(n0 + wm + u) * NP + p) * HH + 8 * g;
    half8 af0 = *(const half8*)(sbase);
    half8 af1 = *(const half8*)(sbase + 32);

    // hoisted adj row pointers (nrow fixed per thread); OOB rows clamped + masked
    const float* arow[4];
    float rowm[4];
#pragma unroll
    for (int r = 0; r < 4; ++r) {
        int nrow = n0 + wm + 4 * g + r;
        rowm[r] = (nrow < NN) ? 1.f : 0.f;
        arow[r] = adj + (size_t)(nrow < NN ? nrow : 0) * NN;
    }

    // staging pointers (advance per k-iter)
    int srow = t >> 2, sch = t & 3;             // Tt: 4 threads/row x 16 f16
    int sm = t >> 3, sch2 = t & 7;              // Sup: 8 threads/row x 8 f16
    const f16* tb_ptr  = Tb + ((size_t)(ks * KITERS * 64 + srow) * NP + p) * HH + sch * 16;
    const f16* sup_ptr = suppT + ((size_t)b * DD + sm) * NNP + ks * KITERS * 64 + sch2 * 8;

    f32x4 acc0 = (f32x4){0.f, 0.f, 0.f, 0.f};
    f32x4 acc1 = (f32x4){0.f, 0.f, 0.f, 0.f};

    // prologue: prefetch k-tile 0 into registers
    half8 rt0 = *(const half8*)(tb_ptr);
    half8 rt1 = *(const half8*)(tb_ptr + 8);
    half8 rs0 = *(const half8*)(sup_ptr);

    for (int kl = 0; kl < KITERS; ++kl) {
        int k0 = (ks * KITERS + kl) * 64;
        // adj loads for this iter (issued early; consumed after GEMM1's 8 MFMAs)
        float av[4][4];
        if (k0 + 64 <= NN) {                    // fast path: no column bounds checks
#pragma unroll
            for (int cc = 0; cc < 4; ++cc) {
                int kcol = k0 + 16 * cc + u;
#pragma unroll
                for (int r = 0; r < 4; ++r) av[cc][r] = rowm[r] * arow[r][kcol];
            }
        } else {                                // boundary k-tile (k0 = 1984)
#pragma unroll
            for (int cc = 0; cc < 4; ++cc) {
                int kcol = k0 + 16 * cc + u;
#pragma unroll
                for (int r = 0; r < 4; ++r)
                    av[cc][r] = (kcol < NN) ? rowm[r] * arow[r][kcol] : 0.f;
            }
        }
        __syncthreads();                        // prev iter done reading LDS
        *(half8*)&Tt[srow][sch * 16]     = rt0;
        *(half8*)&Tt[srow][sch * 16 + 8] = rt1;
        *(half8*)&Sup[sm][sch2 * 8]      = rs0;
        __syncthreads();                        // LDS ready
        if (kl + 1 < KITERS) {                  // prefetch next k-tile (hidden under GEMMs)
            tb_ptr  += (size_t)64 * NP * HH;
            sup_ptr += 64;
            rt0 = *(const half8*)(tb_ptr);
            rt1 = *(const half8*)(tb_ptr + 8);
            rs0 = *(const half8*)(sup_ptr);
        }
        // GEMM1: P = S·T^T over h (K=64 = 2 MFMA), then relu*adj -> Pt (f16)
#pragma unroll
        for (int cc = 0; cc < 4; ++cc) {
            half8 bf0 = *(const half8*)&Tt[16 * cc + u][8 * g];
            half8 bf1 = *(const half8*)&Tt[16 * cc + u][32 + 8 * g];
            f32x4 pacc = (f32x4){0.f, 0.f, 0.f, 0.f};
            pacc = __builtin_amdgcn_mfma_f32_16x16x32_f16(af0, bf0, pacc, 0, 0, 0);
            pacc = __builtin_amdgcn_mfma_f32_16x16x32_f16(af1, bf1, pacc, 0, 0, 0);
#pragma unroll
            for (int r = 0; r < 4; ++r)         // D layout: row = 4g+r, col = u (m89)
                Pt[wm + 4 * g + r][16 * cc + u] = (f16)(fmaxf(pacc[r], 0.f) * av[cc][r]);
        }
        __syncthreads();
        // GEMM2: acc += Pt · Sup  (K=64 = 2 MFMA steps, 2 output col-halves)
#pragma unroll
        for (int s = 0; s < 2; ++s) {
            half8 paf  = *(const half8*)&Pt[wm + u][32 * s + 8 * g];
            half8 sbf0 = *(const half8*)&Sup[u][32 * s + 8 * g];
            half8 sbf1 = *(const half8*)&Sup[16 + u][32 * s + 8 * g];
            acc0 = __builtin_amdgcn_mfma_f32_16x16x32_f16(paf, sbf0, acc0, 0, 0, 0);
            acc1 = __builtin_amdgcn_mfma_f32_16x16x32_f16(paf, sbf1, acc1, 0, 0, 0);
        }
    }
    // epilogue: atomic accumulate into accbuf (pad rows hold zeros, harmless)
#pragma unroll
    for (int r = 0; r < 4; ++r) {
        int nrow = n0 + wm + 4 * g + r;
        size_t o = ((size_t)b * NNP + nrow) * DD + u;
        atomicAdd(&accbuf[o], acc0[r]);
        atomicAdd(&accbuf[o + 16], acc1[r]);
    }
}

// ---- finalize: out = relu(accbuf + bias + resd) ----
__global__ __launch_bounds__(256) void k_fin(const float* __restrict__ accbuf,
                                             const float* __restrict__ resd,
                                             const float* __restrict__ bias,
                                             float* __restrict__ out) {
    int idx = blockIdx.x * 256 + threadIdx.x;   // float4 units over [NB][NN][DD]
    if (idx >= NB * NN * (DD / 4)) return;
    int m4 = idx & 7;
    int n = (idx >> 3) % NN;
    int b = idx / (NN * 8);
    float4 a = ((const float4*)accbuf)[((size_t)b * NNP + n) * 8 + m4];
    float4 rs = ((const float4*)resd)[(size_t)idx];
    float4 bv = ((const float4*)bias)[m4];
    float4 o = make_float4(fmaxf(a.x + bv.x + rs.x, 0.f), fmaxf(a.y + bv.y + rs.y, 0.f),
                           fmaxf(a.z + bv.z + rs.z, 0.f), fmaxf(a.w + bv.w + rs.w, 0.f));
    ((float4*)out)[(size_t)idx] = o;
}

extern "C" void kernel_launch(void* const* d_in, const int* in_sizes, int n_in,
                              void* d_out, int out_size, void* d_ws, size_t ws_size,
                              hipStream_t stream) {
    const float* x    = (const float*)d_in[0];
    const int*   cyc  = (const int*)d_in[1];
    const float* adj  = (const float*)d_in[2];
    const float* envf = (const float*)d_in[3];
    const float* Wenv = (const float*)d_in[4];
    const float* benv = (const float*)d_in[5];
    const float* src  = (const float*)d_in[6];
    const float* tgt  = (const float*)d_in[7];
    const float* W    = (const float*)d_in[8];
    const float* bias = (const float*)d_in[9];
    const float* Wres = (const float*)d_in[10];
    const float* bres = (const float*)d_in[11];
    float* out = (float*)d_out;
    char* ws = (char*)d_ws;

    // ws layout (bytes, 16B-aligned), total ~33.4 MB
    f16*   Sb     = (f16*)(ws + 0);            //  6,291,456  [2048][24][64]
    f16*   Tb     = (f16*)(ws + 6291456);      //  6,291,456  [2048][24][64]
    f16*   suppT  = (f16*)(ws + 12582912);     //  4,194,304  [32][32][2048]
    float* resd   = (float*)(ws + 16777216);   //  8,192,000  [32][2000][32]
    float* accbuf = (float*)(ws + 24969216);   //  8,388,608  [32][2048][32]

    hipLaunchKernelGGL(k_pre, dim3(2816), dim3(256), 0, stream,
                       envf, Wenv, benv, src, tgt, x, W, Wres, bres,
                       Sb, Tb, suppT, resd, accbuf);
    hipLaunchKernelGGL(k_conv2, dim3(NT * KSPLIT * NB), dim3(256), 0, stream,
                       Sb, Tb, suppT, adj, cyc, accbuf);
    hipLaunchKernelGGL(k_fin, dim3((NB * NN * (DD / 4) + 255) / 256), dim3(256), 0, stream,
                       accbuf, resd, bias, out);
}

// Round 11
// 185.998 us; speedup vs baseline: 1.1027x; 1.1027x over previous
//
#include <hip/hip_runtime.h>
#include <hip/hip_bf16.h>
#include <cstdint>

#define NN 2000   // nodes
#define NNP 2048  // padded nodes
#define NB 32     // batch
#define DD 32     // d_in == d_out
#define HH 64     // hidden
#define EE 16     // env features
#define NP 24     // periods
#define NT 32     // n-tiles of 64 (covers 2048)
#define KSPLIT 2  // k-range split per output tile
#define KITERS (NNP / 64 / KSPLIT)   // 16
#define LSTR 68   // LDS row stride in f16 (136 B: 2-bank row step -> conflict-free, proven r5-r7)

typedef _Float16 f16;
typedef unsigned int u32;
typedef _Float16 half8 __attribute__((ext_vector_type(8)));
typedef _Float16 half4v __attribute__((ext_vector_type(4)));
typedef __fp16 fp16v2 __attribute__((ext_vector_type(2)));   // cvt_pkrtz return type
typedef float f32x4 __attribute__((ext_vector_type(4)));

__device__ __forceinline__ half8 ldh8(const f16* p) {   // 8B-aligned LDS read as 2x b64
    half4v lo = *(const half4v*)p;
    half4v hi = *(const half4v*)(p + 4);
    return (half8){lo[0], lo[1], lo[2], lo[3], hi[0], hi[1], hi[2], hi[3]};
}
__device__ __forceinline__ u32 h2u(fp16v2 h) { union { fp16v2 h; u32 w; } x; x.h = h; return x.w; }

// ---- fused prologue: [0,512) prep Sb/Tb; [512,768) suppT+resd; [768,2816) zero accbuf ----
__global__ __launch_bounds__(256) void k_pre(const float* __restrict__ envf,
                                             const float* __restrict__ Wenv,
                                             const float* __restrict__ benv,
                                             const float* __restrict__ src,
                                             const float* __restrict__ tgt,
                                             const float* __restrict__ x,
                                             const float* __restrict__ W,
                                             const float* __restrict__ Wres,
                                             const float* __restrict__ bres,
                                             f16* __restrict__ Sb,
                                             f16* __restrict__ Tb,
                                             f16* __restrict__ suppT,
                                             float* __restrict__ resd,
                                             float* __restrict__ accbuf) {
    int blk = blockIdx.x, t = threadIdx.x;
    if (blk < 512) {
        int n = blk * 4 + (t >> 6), h = t & 63;
        if (n >= NN) {                          // zero pad rows 2000..2047
            for (int p = 0; p < NP; ++p) {
                size_t o = ((size_t)n * NP + p) * HH + h;
                Sb[o] = (f16)0.f; Tb[o] = (f16)0.f;
            }
            return;
        }
        float acc = benv[h];
#pragma unroll
        for (int e = 0; e < EE; ++e) acc = fmaf(envf[n * EE + e], Wenv[e * HH + h], acc);
        acc = fmaxf(acc, 0.f);
        for (int p = 0; p < NP; ++p) {
            size_t i = ((size_t)p * NN + n) * HH + h;
            size_t o = ((size_t)n * NP + p) * HH + h;
            Sb[o] = (f16)(src[i] + acc);
            Tb[o] = (f16)(tgt[i] + acc);
        }
    } else if (blk < 768) {
        __shared__ float w[DD * DD], wr[DD * DD];
        for (int i = t; i < DD * DD; i += 256) { w[i] = W[i]; wr[i] = Wres[i]; }
        __syncthreads();
        int idx = (blk - 512) * 256 + t;        // b*2048 + node
        int b = idx >> 11, node = idx & (NNP - 1);
        if (node >= NN) {
#pragma unroll
            for (int m = 0; m < DD; ++m) suppT[((size_t)b * DD + m) * NNP + node] = (f16)0.f;
            return;
        }
        float xv[DD];
        const float4* xr = (const float4*)(x + ((size_t)b * NN + node) * DD);
#pragma unroll
        for (int q = 0; q < DD / 4; ++q) {
            float4 v = xr[q];
            xv[4 * q] = v.x; xv[4 * q + 1] = v.y; xv[4 * q + 2] = v.z; xv[4 * q + 3] = v.w;
        }
        float sa[DD], ra[DD];
#pragma unroll
        for (int m = 0; m < DD; ++m) { sa[m] = 0.f; ra[m] = bres[m]; }
#pragma unroll
        for (int d = 0; d < DD; ++d) {
            float xd = xv[d];
#pragma unroll
            for (int m = 0; m < DD; ++m) {
                sa[m] = fmaf(xd, w[d * DD + m], sa[m]);
                ra[m] = fmaf(xd, wr[d * DD + m], ra[m]);
            }
        }
#pragma unroll
        for (int m = 0; m < DD; ++m)
            suppT[((size_t)b * DD + m) * NNP + node] = (f16)sa[m];
        float4* ro = (float4*)(resd + ((size_t)b * NN + node) * DD);
#pragma unroll
        for (int q = 0; q < DD / 4; ++q)
            ro[q] = make_float4(fmaxf(ra[4 * q], 0.f), fmaxf(ra[4 * q + 1], 0.f),
                                fmaxf(ra[4 * q + 2], 0.f), fmaxf(ra[4 * q + 3], 0.f));
    } else {
        int i = (blk - 768) * 256 + t;          // float4 units; covers 524288
        ((float4*)accbuf)[i] = make_float4(0.f, 0.f, 0.f, 0.f);
    }
}

// ---- main: swapped-GEMM1 + in-register P handoff; dbuf LDS, 1 barrier/iter ----
__global__ __launch_bounds__(256, 4) void k_conv2(const f16* __restrict__ Sb,    // [NNP,NP,HH]
                                                  const f16* __restrict__ Tb,    // [NNP,NP,HH]
                                                  const f16* __restrict__ suppT, // [NB,DD,NNP]
                                                  const float* __restrict__ adj, // [NN,NN]
                                                  const int* __restrict__ cyc,   // [NB]
                                                  float* __restrict__ accbuf) {  // [NB,NNP,DD]
    int bi = blockIdx.x;
    int b = bi & 31;                 // b fastest: co-resident blocks share adj n-panel in L2
    int ks = (bi >> 5) & (KSPLIT - 1);
    int nt = bi >> 6;
    int p = cyc[b] % NP; if (p < 0) p += NP;

    __shared__ f16 Tt[2][64][LSTR];
    __shared__ f16 Sup[2][DD][LSTR];

    int t = threadIdx.x;
    int w = t >> 6, l = t & 63;
    int u = l & 15, g = l >> 4;      // MFMA lane decomposition
    int wm = w * 16;                 // wave's 16 n-rows
    int n0 = nt * 64;

    // S fragment = B-operand of swapped GEMM1 (this lane's n-row), k-loop invariant
    const f16* sbase = Sb + ((size_t)(n0 + wm + u) * NP + p) * HH + 8 * g;
    half8 af0 = *(const half8*)(sbase);         // h = 8g+j
    half8 af1 = *(const half8*)(sbase + 32);    // h = 32+8g+j

    // adj row for this lane's n-column (P^T: n = u is lane-local)
    int n = n0 + wm + u;
    float rowm = (n < NN) ? 1.f : 0.f;
    const float* arow = adj + (size_t)(n < NN ? n : 0) * NN;

    // staging decomposition
    int srow = t >> 2, sch = t & 3;             // Tt: 4 threads/row x 16 f16
    int sm = t >> 3, sch2 = t & 7;              // Sup: 8 threads/row x 8 f16
    const f16* tb_ptr  = Tb + ((size_t)(ks * KITERS * 64 + srow) * NP + p) * HH + sch * 16;
    const f16* sup_ptr = suppT + ((size_t)b * DD + sm) * NNP + ks * KITERS * 64 + sch2 * 8;

    // shuffle sources for the P handoff (derived mapping, constant per lane)
    int srcA = u + ((g & 1) << 5);
    int srcB = srcA + 16;
    bool chi = (g >> 1) != 0;

    f32x4 acc0 = (f32x4){0.f, 0.f, 0.f, 0.f};
    f32x4 acc1 = (f32x4){0.f, 0.f, 0.f, 0.f};

    // prologue: load tile0 -> write buf0 -> load tile1 into regs
    half8 rt0 = *(const half8*)(tb_ptr);
    half8 rt1 = *(const half8*)(tb_ptr + 8);
    half8 rs0 = *(const half8*)(sup_ptr);
    *(half4v*)&Tt[0][srow][sch * 16]      = (half4v){rt0[0], rt0[1], rt0[2], rt0[3]};
    *(half4v*)&Tt[0][srow][sch * 16 + 4]  = (half4v){rt0[4], rt0[5], rt0[6], rt0[7]};
    *(half4v*)&Tt[0][srow][sch * 16 + 8]  = (half4v){rt1[0], rt1[1], rt1[2], rt1[3]};
    *(half4v*)&Tt[0][srow][sch * 16 + 12] = (half4v){rt1[4], rt1[5], rt1[6], rt1[7]};
    *(half4v*)&Sup[0][sm][sch2 * 8]       = (half4v){rs0[0], rs0[1], rs0[2], rs0[3]};
    *(half4v*)&Sup[0][sm][sch2 * 8 + 4]   = (half4v){rs0[4], rs0[5], rs0[6], rs0[7]};
    tb_ptr  += (size_t)64 * NP * HH;
    sup_ptr += 64;
    rt0 = *(const half8*)(tb_ptr);
    rt1 = *(const half8*)(tb_ptr + 8);
    rs0 = *(const half8*)(sup_ptr);

    for (int kl = 0; kl < KITERS; ++kl) {
        int k0 = (ks * KITERS + kl) * 64;
        int cur = kl & 1, nxt = cur ^ 1;
        // adj loads for this tile (early issue; consumed after GEMM1 MFMAs)
        f32x4 av[4];
        if (k0 + 64 <= NN) {                    // fast path: whole k-tile in bounds
#pragma unroll
            for (int cc = 0; cc < 4; ++cc) {
                float4 a4 = *(const float4*)(arow + k0 + 16 * cc + 4 * g);
                av[cc] = (f32x4){a4.x * rowm, a4.y * rowm, a4.z * rowm, a4.w * rowm};
            }
        } else {                                // boundary k-tile (k0 = 1984)
#pragma unroll
            for (int cc = 0; cc < 4; ++cc)
#pragma unroll
                for (int r = 0; r < 4; ++r) {
                    int kcol = k0 + 16 * cc + 4 * g + r;
                    av[cc][r] = (kcol < NN) ? rowm * arow[kcol] : 0.f;
                }
        }
        __syncthreads();   // buf[cur] (tile kl) visible; buf[nxt] reads (tile kl-1) done
        if (kl + 1 < KITERS) {                  // write tile kl+1 (overlaps compute below)
            *(half4v*)&Tt[nxt][srow][sch * 16]      = (half4v){rt0[0], rt0[1], rt0[2], rt0[3]};
            *(half4v*)&Tt[nxt][srow][sch * 16 + 4]  = (half4v){rt0[4], rt0[5], rt0[6], rt0[7]};
            *(half4v*)&Tt[nxt][srow][sch * 16 + 8]  = (half4v){rt1[0], rt1[1], rt1[2], rt1[3]};
            *(half4v*)&Tt[nxt][srow][sch * 16 + 12] = (half4v){rt1[4], rt1[5], rt1[6], rt1[7]};
            *(half4v*)&Sup[nxt][sm][sch2 * 8]       = (half4v){rs0[0], rs0[1], rs0[2], rs0[3]};
            *(half4v*)&Sup[nxt][sm][sch2 * 8 + 4]   = (half4v){rs0[4], rs0[5], rs0[6], rs0[7]};
        }
        if (kl + 2 < KITERS) {                  // prefetch tile kl+2 into regs
            tb_ptr  += (size_t)64 * NP * HH;
            sup_ptr += 64;
            rt0 = *(const half8*)(tb_ptr);
            rt1 = *(const half8*)(tb_ptr + 8);
            rs0 = *(const half8*)(sup_ptr);
        }
        // GEMM1 (swapped): pacc[cc] = P^T rows k_local=4g+r, col n=u; then relu*adj, pack f16
        u32 w16[8];
#pragma unroll
        for (int cc = 0; cc < 4; ++cc) {
            half8 tf0 = ldh8(&Tt[cur][16 * cc + u][8 * g]);
            half8 tf1 = ldh8(&Tt[cur][16 * cc + u][32 + 8 * g]);
            f32x4 pacc = (f32x4){0.f, 0.f, 0.f, 0.f};
            pacc = __builtin_amdgcn_mfma_f32_16x16x32_f16(tf0, af0, pacc, 0, 0, 0);
            pacc = __builtin_amdgcn_mfma_f32_16x16x32_f16(tf1, af1, pacc, 0, 0, 0);
            float v0 = fmaxf(pacc[0], 0.f) * av[cc][0];
            float v1 = fmaxf(pacc[1], 0.f) * av[cc][1];
            float v2 = fmaxf(pacc[2], 0.f) * av[cc][2];
            float v3 = fmaxf(pacc[3], 0.f) * av[cc][3];
            w16[cc * 2]     = h2u(__builtin_amdgcn_cvt_pkrtz(v0, v1));
            w16[cc * 2 + 1] = h2u(__builtin_amdgcn_cvt_pkrtz(v2, v3));
        }
        // P handoff: lane (u,g) pulls reg cc=2s+(g>>1), words 0/1, from srcA/srcB
#pragma unroll
        for (int s = 0; s < 2; ++s) {
            u32 aw0 = (u32)__shfl((int)w16[4 * s + 0], srcA);
            u32 aw1 = (u32)__shfl((int)w16[4 * s + 1], srcA);
            u32 ah0 = (u32)__shfl((int)w16[4 * s + 2], srcA);
            u32 ah1 = (u32)__shfl((int)w16[4 * s + 3], srcA);
            u32 bw0 = (u32)__shfl((int)w16[4 * s + 0], srcB);
            u32 bw1 = (u32)__shfl((int)w16[4 * s + 1], srcB);
            u32 bh0 = (u32)__shfl((int)w16[4 * s + 2], srcB);
            u32 bh1 = (u32)__shfl((int)w16[4 * s + 3], srcB);
            union { u32 w[4]; half8 h; } ph;
            ph.w[0] = chi ? ah0 : aw0;
            ph.w[1] = chi ? ah1 : aw1;
            ph.w[2] = chi ? bh0 : bw0;
            ph.w[3] = chi ? bh1 : bw1;
            half8 sb0 = ldh8(&Sup[cur][u][32 * s + 8 * g]);
            half8 sb1 = ldh8(&Sup[cur][16 + u][32 * s + 8 * g]);
            acc0 = __builtin_amdgcn_mfma_f32_16x16x32_f16(ph.h, sb0, acc0, 0, 0, 0);
            acc1 = __builtin_amdgcn_mfma_f32_16x16x32_f16(ph.h, sb1, acc1, 0, 0, 0);
        }
    }
    // epilogue: atomic accumulate (pad rows land in accbuf pad, ignored by k_fin)
#pragma unroll
    for (int r = 0; r < 4; ++r) {
        int nrow = n0 + wm + 4 * g + r;
        size_t o = ((size_t)b * NNP + nrow) * DD + u;
        atomicAdd(&accbuf[o], acc0[r]);
        atomicAdd(&accbuf[o + 16], acc1[r]);
    }
}

// ---- finalize: out = relu(accbuf + bias + resd) ----
__global__ __launch_bounds__(256) void k_fin(const float* __restrict__ accbuf,
                                             const float* __restrict__ resd,
                                             const float* __restrict__ bias,
                                             float* __restrict__ out) {
    int idx = blockIdx.x * 256 + threadIdx.x;   // float4 units over [NB][NN][DD]
    if (idx >= NB * NN * (DD / 4)) return;
    int m4 = idx & 7;
    int n = (idx >> 3) % NN;
    int b = idx / (NN * 8);
    float4 a = ((const float4*)accbuf)[((size_t)b * NNP + n) * 8 + m4];
    float4 rs = ((const float4*)resd)[(size_t)idx];
    float4 bv = ((const float4*)bias)[m4];
    float4 o = make_float4(fmaxf(a.x + bv.x + rs.x, 0.f), fmaxf(a.y + bv.y + rs.y, 0.f),
                           fmaxf(a.z + bv.z + rs.z, 0.f), fmaxf(a.w + bv.w + rs.w, 0.f));
    ((float4*)out)[(size_t)idx] = o;
}

extern "C" void kernel_launch(void* const* d_in, const int* in_sizes, int n_in,
                              void* d_out, int out_size, void* d_ws, size_t ws_size,
                              hipStream_t stream) {
    const float* x    = (const float*)d_in[0];
    const int*   cyc  = (const int*)d_in[1];
    const float* adj  = (const float*)d_in[2];
    const float* envf = (const float*)d_in[3];
    const float* Wenv = (const float*)d_in[4];
    const float* benv = (const float*)d_in[5];
    const float* src  = (const float*)d_in[6];
    const float* tgt  = (const float*)d_in[7];
    const float* W    = (const float*)d_in[8];
    const float* bias = (const float*)d_in[9];
    const float* Wres = (const float*)d_in[10];
    const float* bres = (const float*)d_in[11];
    float* out = (float*)d_out;
    char* ws = (char*)d_ws;

    // ws layout (bytes, 16B-aligned), total ~33.4 MB
    f16*   Sb     = (f16*)(ws + 0);            //  6,291,456  [2048][24][64]
    f16*   Tb     = (f16*)(ws + 6291456);      //  6,291,456  [2048][24][64]
    f16*   suppT  = (f16*)(ws + 12582912);     //  4,194,304  [32][32][2048]
    float* resd   = (float*)(ws + 16777216);   //  8,192,000  [32][2000][32]
    float* accbuf = (float*)(ws + 24969216);   //  8,388,608  [32][2048][32]

    hipLaunchKernelGGL(k_pre, dim3(2816), dim3(256), 0, stream,
                       envf, Wenv, benv, src, tgt, x, W, Wres, bres,
                       Sb, Tb, suppT, resd, accbuf);
    hipLaunchKernelGGL(k_conv2, dim3(NT * KSPLIT * NB), dim3(256), 0, stream,
                       Sb, Tb, suppT, adj, cyc, accbuf);
    hipLaunchKernelGGL(k_fin, dim3((NB * NN * (DD / 4) + 255) / 256), dim3(256), 0, stream,
                       accbuf, resd, bias, out);
}